// Round 6
// baseline (1216.273 us; speedup 1.0000x reference)
//
#include <hip/hip_runtime.h>
#include <hip/hip_bf16.h>

// ============================ R17: MEASUREMENT BUILD =====================================
// Production config = R14 (139.2 us). Each kernel body is wrapped in an idempotent REP
// loop with a memory-clobber so loads+compute+stores repeat (no LICM), making every
// kernel's single dispatch long enough to surface in rocprof's top-5 with full counters.
// Per-kernel true time = dur_us / REP. Outputs are bit-identical to R14 (idempotent).
#define REP_PREP 16
#define REP_QKV  8
#define REP_ATTN 8
#define REP_MEGA 8

typedef __hip_bfloat16 bf16;
typedef short short8 __attribute__((ext_vector_type(8)));
typedef float f32x4 __attribute__((ext_vector_type(4)));
typedef unsigned int u32x4 __attribute__((ext_vector_type(4)));

#define C_   128
#define N_   4096
#define NH_  8
#define HD_  16
#define FF_  2048
#define SCALE_Q 0.360673760222241f   // 0.25 * log2(e); attn uses v_exp_f32 (2^x)

__device__ __forceinline__ unsigned short f2bf_bits(float f) {
    bf16 h = __float2bfloat16(f);
    return *reinterpret_cast<unsigned short*>(&h);
}
__device__ __forceinline__ unsigned int pack_trunc(float lo, float hi) {
    return __builtin_amdgcn_perm(__float_as_uint(hi), __float_as_uint(lo), 0x07060302u);
}
__device__ __forceinline__ short f2bf_trunc(float f) {
    return (short)(__float_as_uint(f) >> 16);
}
__device__ __forceinline__ float bfs2f(short s) {
    return __uint_as_float(((unsigned int)(unsigned short)s) << 16);
}
__device__ __forceinline__ float fast_exp2(float x) {
    return __builtin_amdgcn_exp2f(x);
}
__device__ __forceinline__ f32x4 mfma16(short8 a, short8 b, f32x4 c) {
    return __builtin_amdgcn_mfma_f32_16x16x32_bf16(a, b, c, 0, 0, 0);
}

// ---------------- K0: prep — vectorized: one short8 (16B) store per thread ----------
__global__ void __launch_bounds__(256) k_prep(
    const float* __restrict__ Wq, const float* __restrict__ Wk,
    const float* __restrict__ Wv, const float* __restrict__ Wo,
    const float* __restrict__ W1, const float* __restrict__ W2,
    const float* __restrict__ x,
    bf16* __restrict__ Wqkvf, bf16* __restrict__ Wof,
    bf16* __restrict__ W1f, bf16* __restrict__ W2f,
    bf16* __restrict__ xTf)
{
    #pragma unroll 1
    for (int rep = 0; rep < REP_PREP; ++rep) {
        const int i = blockIdx.x * 256 + threadIdx.x;   // [0, 139264)
        if (i < 73728) {
            const float* row;
            bf16* dst;
            int kblk, g;
            if (i < 8192) {                      // QKV (o 0..383) + Wo (o 384..511), K=128
                const int o = i >> 4;
                kblk = (i >> 2) & 3; g = i & 3;
                const int odx = (o < 384) ? o : o - 384;
                row = (o < 128) ? (Wq + o * 128)
                    : (o < 256) ? (Wk + (o - 128) * 128)
                    : (o < 384) ? (Wv + (o - 256) * 128)
                                : (Wo + (o - 384) * 128);
                bf16* buf = (o < 384) ? Wqkvf : Wof;
                dst = buf + ((((odx >> 4) << 2) + kblk) * 512 + ((g << 4) + (odx & 15)) * 8);
            } else if (i < 40960) {              // W1 : [2048][128]
                const int t = i - 8192, o = t >> 4;
                kblk = (t >> 2) & 3; g = t & 3;
                row = W1 + o * 128;
                dst = W1f + ((((o >> 4) << 2) + kblk) * 512 + ((g << 4) + (o & 15)) * 8);
            } else {                             // W2 : [128][2048]
                const int t = i - 40960, o = t >> 8;
                kblk = (t >> 2) & 63; g = t & 3;
                row = W2 + o * 2048;
                dst = W2f + ((((o >> 4) << 6) + kblk) * 512 + ((g << 4) + (o & 15)) * 8);
            }
            const int k0 = kblk * 32 + g * 4;
            const f32x4 lo = *(const f32x4*)(row + k0);
            const f32x4 hi = *(const f32x4*)(row + k0 + 16);
            u32x4 w;
            #pragma unroll
            for (int j = 0; j < 4; ++j)
                w[j] = ((unsigned int)f2bf_bits(hi[j]) << 16) | f2bf_bits(lo[j]);
            *(u32x4*)dst = w;
        } else {                                 // x : [128][4096] -> xTf A-frags
            const int t = i - 73728;             // [0, 65536)
            const int n = t & 4095, g = (t >> 12) & 3, cblk = t >> 14;
            const int c0 = cblk * 32 + g * 4;
            const float* xs = x + (size_t)c0 * 4096 + n;
            u32x4 w;
            #pragma unroll
            for (int j = 0; j < 4; ++j)
                w[j] = ((unsigned int)f2bf_bits(xs[(size_t)(16 + j) * 4096]) << 16)
                     | f2bf_bits(xs[(size_t)j * 4096]);
            bf16* dst = xTf + ((((n >> 4) << 2) + cblk) * 512 + ((g << 4) + (n & 15)) * 8);
            *(u32x4*)dst = w;
        }
        __asm__ __volatile__("" ::: "memory");   // defeat LICM across reps
    }
}

// ---------------- K1: QKV — barrier-free fragment-streaming GEMM ----------------
__global__ void __launch_bounds__(256) k_qkv(
    const bf16* __restrict__ xTf, const bf16* __restrict__ Wqkvf,
    const float* __restrict__ bq, const float* __restrict__ bk, const float* __restrict__ bv,
    bf16* __restrict__ qf, bf16* __restrict__ kf, bf16* __restrict__ vf)
{
    #pragma unroll 1
    for (int rep = 0; rep < REP_QKV; ++rep) {
        const int tid = threadIdx.x, wave = tid >> 6, lane = tid & 63;
        const int col = lane & 15, quad = lane >> 4;
        const int gw = blockIdx.x * 4 + wave;     // [0, 6144)
        const int rt = gw / 24, ct = gw % 24;
        f32x4 acc = {};
        #pragma unroll
        for (int c = 0; c < 4; ++c) {
            short8 a = *(const short8*)(xTf + ((size_t)(rt * 4 + c) << 9) + lane * 8);
            short8 b = *(const short8*)(Wqkvf + ((size_t)(ct * 4 + c) << 9) + lane * 8);
            acc = mfma16(a, b, acc);
        }
        #pragma unroll
        for (int r = 0; r < 4; ++r) {
            const int m = rt * 16 + quad * 4 + r;
            const int n = ct * 16 + col;
            const float v = acc[r];
            if (n < 128) {
                const int h = n >> 4, ch = n & 15;
                qf[((h << 8) + (m >> 4)) * 256 + (((ch >> 3) << 4) + (m & 15)) * 8 + (ch & 7)] =
                    __float2bfloat16((v + bq[n]) * SCALE_Q);
            } else if (n < 256) {
                const int c2 = n - 128, h = c2 >> 4, ch = c2 & 15;
                kf[((h << 8) + (m >> 4)) * 256 + (((ch >> 3) << 4) + (m & 15)) * 8 + (ch & 7)] =
                    __float2bfloat16(v + bk[c2]);
            } else {
                const int c2 = n - 256, h = c2 >> 4, ch = c2 & 15;
                const int ko = m & 31;
                const int pos = ((ko & 15) << 1) + (ko >> 4);
                vf[((h << 7) + (m >> 5)) * 512 + (((pos >> 3) << 4) + ch) * 8 + (pos & 7)] =
                    __float2bfloat16(v + bv[c2]);
            }
        }
        __asm__ __volatile__("" ::: "memory");
    }
}

// ---------------- K2: MFMA flash attention — q-tile grouping for KV L2 reuse (R14) ------
__global__ void __launch_bounds__(256)
attn_kernel(const bf16* __restrict__ qf, const bf16* __restrict__ kf,
            const bf16* __restrict__ vf, bf16* __restrict__ af)
{
    __shared__ __align__(16) union {
        unsigned int P[4][4][2][320];   // [wave][qt][buf] transpose bufs, 40 KB
        float comb[4][4][64][8];        // [qt][wave][lane][O0..3,L0..3], 32 KB
    } sh;
    #pragma unroll 1
    for (int rep = 0; rep < REP_ATTN; ++rep) {
        const int tid = threadIdx.x, wave = tid >> 6, lane = tid & 63;
        const int col = lane & 15, quad = lane >> 4;
        const int gw = blockIdx.x;                   // [0, 512)
        const int h  = gw >> 6;
        const int tile0 = (gw & 63) << 2;
        const f32x4 zero = {};

        short8 aq[4] = {{}, {}, {}, {}};
        if (quad < 2) {
            #pragma unroll
            for (int qt = 0; qt < 4; ++qt)
                aq[qt] = *(const short8*)(qf + ((size_t)((h << 8) + tile0 + qt) << 8) + lane * 8);
        }

        const short8 onesb = { (short)0x3F80, (short)0x3F80, (short)0x3F80, (short)0x3F80,
                               (short)0x3F80, (short)0x3F80, (short)0x3F80, (short)0x3F80 };

        f32x4 accO[4] = {{}, {}, {}, {}};
        f32x4 accL[4] = {{}, {}, {}, {}};

        const int kbeg = wave << 10;

        for (int i = 0; i < 32; i += 2) {
            const int mA = kbeg + (i << 5);
            const int mB = mA + 32;

            short8 bkA0 = {}, bkA1 = {}, bkB0 = {}, bkB1 = {};
            if (quad < 2) {
                const bf16* ka = kf + ((size_t)((h << 8) + (mA >> 4)) << 8) + lane * 8;
                bkA0 = *(const short8*)(ka);
                bkA1 = *(const short8*)(ka + 256);
                bkB0 = *(const short8*)(ka + 512);
                bkB1 = *(const short8*)(ka + 768);
            }
            const short8 vA = *(const short8*)(vf + ((size_t)((h << 7) + (mA >> 5)) << 9) + lane * 8);
            const short8 vB = *(const short8*)(vf + ((size_t)((h << 7) + (mB >> 5)) << 9) + lane * 8);

            #pragma unroll
            for (int qt = 0; qt < 4; ++qt) {
                f32x4 s0 = mfma16(aq[qt], bkA0, zero);
                f32x4 s1 = mfma16(aq[qt], bkA1, zero);
                f32x4 s2 = mfma16(aq[qt], bkB0, zero);
                f32x4 s3 = mfma16(aq[qt], bkB1, zero);
                unsigned int* P0 = &sh.P[wave][qt][0][0];
                unsigned int* P1 = &sh.P[wave][qt][1][0];
                #pragma unroll
                for (int r = 0; r < 4; ++r) {
                    P0[(quad * 4 + r) * 20 + col] = pack_trunc(fast_exp2(s0[r]), fast_exp2(s1[r]));
                    P1[(quad * 4 + r) * 20 + col] = pack_trunc(fast_exp2(s2[r]), fast_exp2(s3[r]));
                }
            }
            #pragma unroll
            for (int qt = 0; qt < 4; ++qt) {
                const short* Ps0 = (const short*)&sh.P[wave][qt][0][0];
                const short* Ps1 = (const short*)&sh.P[wave][qt][1][0];
                short8 ap0 = *(const short8*)(Ps0 + col * 40 + quad * 8);
                accO[qt] = mfma16(ap0, vA, accO[qt]);
                accL[qt] = mfma16(ap0, onesb, accL[qt]);
                short8 ap1 = *(const short8*)(Ps1 + col * 40 + quad * 8);
                accO[qt] = mfma16(ap1, vB, accO[qt]);
                accL[qt] = mfma16(ap1, onesb, accL[qt]);
            }
        }

        __syncthreads();
        #pragma unroll
        for (int qt = 0; qt < 4; ++qt)
            #pragma unroll
            for (int r = 0; r < 4; ++r) {
                sh.comb[qt][wave][lane][r]     = accO[qt][r];
                sh.comb[qt][wave][lane][4 + r] = accL[qt][r];
            }
        __syncthreads();

        {   // wave w finalizes q-tile w
            const int qt = wave, tile = tile0 + qt;
            #pragma unroll
            for (int r = 0; r < 4; ++r) {
                float O = sh.comb[qt][0][lane][r] + sh.comb[qt][1][lane][r]
                        + sh.comb[qt][2][lane][r] + sh.comb[qt][3][lane][r];
                float l = sh.comb[qt][0][lane][4+r] + sh.comb[qt][1][lane][4+r]
                        + sh.comb[qt][2][lane][4+r] + sh.comb[qt][3][lane][4+r];
                const int row16 = quad * 4 + r;
                const int pk = (col << 1) + (h & 1);
                af[((tile << 2) + (h >> 1)) * 512 + (((pk >> 3) << 4) + row16) * 8 + (pk & 7)] =
                    __float2bfloat16(O / l);
            }
        }
        __syncthreads();                         // rep boundary: P/comb union reuse
        __asm__ __volatile__("" ::: "memory");
    }
}

// ---------------- K3: MEGA — 8 waves (2/SIMD); tree-combine in LDS (R13) ----------------
__global__ void __launch_bounds__(512, 2)
k_mega(const bf16* __restrict__ af, const bf16* __restrict__ xTf,
       const bf16* __restrict__ Wof, const bf16* __restrict__ W1f, const bf16* __restrict__ W2f,
       const float* __restrict__ bo, const float* __restrict__ b1, const float* __restrict__ b2,
       const float* __restrict__ g1, const float* __restrict__ be1,
       const float* __restrict__ g2, const float* __restrict__ be2,
       float* __restrict__ out)
{
    __shared__ __align__(16) unsigned int Pb[8][2][320];   // per-wave transpose dbuf (20 KB)
    __shared__ float comb[224][64];                         // ffn2 partials, waves 1-7 (56 KB)
    #pragma unroll 1
    for (int rep = 0; rep < REP_MEGA; ++rep) {
        const int tid = threadIdx.x, wave = tid >> 6, lane = tid & 63;
        const int col = lane & 15, quad = lane >> 4;
        const int rt = blockIdx.x, n0 = rt << 4;
        const f32x4 zero = {};

        short8 ao[4], xt[4];
        #pragma unroll
        for (int c = 0; c < 4; ++c) {
            ao[c] = *(const short8*)(af  + ((size_t)(rt * 4 + c) << 9) + lane * 8);
            xt[c] = *(const short8*)(xTf + ((size_t)(rt * 4 + c) << 9) + lane * 8);
        }
        f32x4 d[8];
        #pragma unroll
        for (int t = 0; t < 8; ++t) d[t] = zero;
        #pragma unroll
        for (int t = 0; t < 8; ++t)
            #pragma unroll
            for (int c = 0; c < 4; ++c) {
                short8 b = *(const short8*)(Wof + ((size_t)(t * 4 + c) << 9) + lane * 8);
                d[t] = mfma16(ao[c], b, d[t]);
            }
        #pragma unroll
        for (int t = 0; t < 8; ++t) {
            const float bt = bo[t * 16 + col];
            #pragma unroll
            for (int r = 0; r < 4; ++r) d[t][r] += bt;
        }

        float x1f[4][8];
        #pragma unroll
        for (int c = 0; c < 4; ++c) {
            unsigned int* Pw = &Pb[wave][c & 1][0];
            const short* Ps = (const short*)Pw;
            #pragma unroll
            for (int r = 0; r < 4; ++r)
                Pw[(quad * 4 + r) * 20 + col] = pack_trunc(d[2 * c][r], d[2 * c + 1][r]);
            short8 ar = *(const short8*)(Ps + col * 40 + quad * 8);
            #pragma unroll
            for (int j = 0; j < 8; ++j)
                x1f[c][j] = bfs2f(ar[j]) + bfs2f(xt[c][j]);
        }

        float s = 0.f, ss = 0.f;
        #pragma unroll
        for (int c = 0; c < 4; ++c)
            #pragma unroll
            for (int j = 0; j < 8; ++j) { s += x1f[c][j]; ss += x1f[c][j] * x1f[c][j]; }
        s  += __shfl_xor(s, 16);  s  += __shfl_xor(s, 32);
        ss += __shfl_xor(ss, 16); ss += __shfl_xor(ss, 32);
        const float m1 = s * (1.f / 128.f);
        const float rstd1 = rsqrtf(ss * (1.f / 128.f) - m1 * m1 + 1e-5f);
        short8 aq1[4];
        #pragma unroll
        for (int c = 0; c < 4; ++c)
            #pragma unroll
            for (int j = 0; j < 8; ++j) {
                const int pos = quad * 8 + j;
                const int ko = ((pos & 1) << 4) + (pos >> 1);
                const int ch = c * 32 + ko;
                aq1[c][j] = f2bf_trunc((x1f[c][j] - m1) * rstd1 * g1[ch] + be1[ch]);
            }

        f32x4 ACC[8];
        #pragma unroll
        for (int t = 0; t < 8; ++t) ACC[t] = zero;
        for (int i = 0; i < 8; ++i) {
            const int ffc = (wave << 3) + i;                  // global 32-FF chunk [0,64)
            f32x4 p0 = zero, p1 = zero;
            #pragma unroll
            for (int c = 0; c < 4; ++c) {
                short8 b = *(const short8*)(W1f + ((size_t)(ffc * 8 + c) << 9) + lane * 8);
                p0 = mfma16(aq1[c], b, p0);
            }
            #pragma unroll
            for (int c = 0; c < 4; ++c) {
                short8 b = *(const short8*)(W1f + ((size_t)(ffc * 8 + 4 + c) << 9) + lane * 8);
                p1 = mfma16(aq1[c], b, p1);
            }
            const float bb0 = b1[ffc * 32 + col], bb1 = b1[ffc * 32 + 16 + col];
            unsigned int* Pw = &Pb[wave][i & 1][0];
            #pragma unroll
            for (int r = 0; r < 4; ++r)
                Pw[(quad * 4 + r) * 20 + col] =
                    pack_trunc(fmaxf(p0[r] + bb0, 0.f), fmaxf(p1[r] + bb1, 0.f));
            short8 ah = *(const short8*)((const short*)Pw + col * 40 + quad * 8);
            #pragma unroll
            for (int t = 0; t < 8; ++t) {
                short8 bw = *(const short8*)(W2f + ((size_t)(t * 64 + ffc) << 9) + lane * 8);
                ACC[t] = mfma16(ah, bw, ACC[t]);
            }
        }

        if (wave) {
            #pragma unroll
            for (int t = 0; t < 8; ++t)
                #pragma unroll
                for (int r = 0; r < 4; ++r)
                    comb[(wave - 1) * 32 + t * 4 + r][lane] = ACC[t][r];
        }
        __syncthreads();
        if (wave == 0) {
            #pragma unroll
            for (int t = 0; t < 8; ++t)
                #pragma unroll
                for (int r = 0; r < 4; ++r) {
                    float acc = ACC[t][r];
                    #pragma unroll
                    for (int w = 0; w < 7; ++w)
                        acc += comb[w * 32 + t * 4 + r][lane];
                    ACC[t][r] = acc;
                }
            short* xb = (short*)&Pb[0][0][0];   // [row16][chunk][32 pk] = 4096 shorts
            #pragma unroll
            for (int c = 0; c < 4; ++c)
                *(short8*)(xb + (col * 4 + c) * 32 + quad * 8) = aq1[c];
            float t2[8][4];
            #pragma unroll
            for (int t = 0; t < 8; ++t) {
                const int ch = t * 16 + col;
                const int pk = (col << 1) + (t & 1);
                const int c = t >> 1;
                const float bb = b2[ch];
                #pragma unroll
                for (int r = 0; r < 4; ++r)
                    t2[t][r] = ACC[t][r] + bb + bfs2f(xb[((quad * 4 + r) * 4 + c) * 32 + pk]);
            }
            #pragma unroll
            for (int r = 0; r < 4; ++r) {
                float S = 0.f, SS = 0.f;
                #pragma unroll
                for (int t = 0; t < 8; ++t) { S += t2[t][r]; SS += t2[t][r] * t2[t][r]; }
                S  += __shfl_xor(S, 1);  S  += __shfl_xor(S, 2);
                S  += __shfl_xor(S, 4);  S  += __shfl_xor(S, 8);
                SS += __shfl_xor(SS, 1); SS += __shfl_xor(SS, 2);
                SS += __shfl_xor(SS, 4); SS += __shfl_xor(SS, 8);
                const float m2 = S * (1.f / 128.f);
                const float rstd2 = rsqrtf(SS * (1.f / 128.f) - m2 * m2 + 1e-5f);
                #pragma unroll
                for (int t = 0; t < 8; ++t) {
                    const int ch = t * 16 + col;
                    out[(size_t)ch * N_ + n0 + quad * 4 + r] =
                        (t2[t][r] - m2) * rstd2 * g2[ch] + be2[ch];
                }
            }
        }
        __syncthreads();                         // rep boundary: Pb/comb reuse
        __asm__ __volatile__("" ::: "memory");
    }
}

extern "C" void kernel_launch(void* const* d_in, const int* in_sizes, int n_in,
                              void* d_out, int out_size, void* d_ws, size_t ws_size,
                              hipStream_t stream) {
    const float* x   = (const float*)d_in[0];
    const float* Wq  = (const float*)d_in[1];
    const float* bq  = (const float*)d_in[2];
    const float* Wk  = (const float*)d_in[3];
    const float* bk  = (const float*)d_in[4];
    const float* Wv  = (const float*)d_in[5];
    const float* bv  = (const float*)d_in[6];
    const float* Wo  = (const float*)d_in[7];
    const float* bo  = (const float*)d_in[8];
    const float* W1  = (const float*)d_in[9];
    const float* b1  = (const float*)d_in[10];
    const float* W2  = (const float*)d_in[11];
    const float* b2  = (const float*)d_in[12];
    const float* g1  = (const float*)d_in[13];
    const float* be1 = (const float*)d_in[14];
    const float* g2  = (const float*)d_in[15];
    const float* be2 = (const float*)d_in[16];
    float* out = (float*)d_out;

    char* ws = (char*)d_ws;
    bf16* xTf   = (bf16*)(ws + 0);          // 1 MB
    bf16* qf    = (bf16*)(ws + 1048576);    // 1 MB
    bf16* kf    = (bf16*)(ws + 2097152);    // 1 MB
    bf16* vf    = (bf16*)(ws + 3145728);    // 1 MB
    bf16* af    = (bf16*)(ws + 4194304);    // 1 MB
    bf16* Wqkvf = (bf16*)(ws + 5242880);    // 96 KB
    bf16* Wof   = (bf16*)(ws + 5341184);    // 32 KB
    bf16* W1f   = (bf16*)(ws + 5373952);    // 512 KB
    bf16* W2f   = (bf16*)(ws + 5898240);    // 512 KB

    k_prep<<<544, 256, 0, stream>>>(Wq, Wk, Wv, Wo, W1, W2, x, Wqkvf, Wof, W1f, W2f, xTf);
    k_qkv<<<1536, 256, 0, stream>>>(xTf, Wqkvf, bq, bk, bv, qf, kf, vf);
    attn_kernel<<<512, 256, 0, stream>>>(qf, kf, vf, af);
    k_mega<<<256, 512, 0, stream>>>(af, xTf, Wof, W1f, W2f, bo, b1, b2,
                                    g1, be1, g2, be2, out);
}

// Round 7
// 148.836 us; speedup vs baseline: 8.1719x; 8.1719x over previous
//
#include <hip/hip_runtime.h>
#include <hip/hip_bf16.h>

typedef __hip_bfloat16 bf16;
typedef short short8 __attribute__((ext_vector_type(8)));
typedef float f32x4 __attribute__((ext_vector_type(4)));
typedef unsigned int u32x4 __attribute__((ext_vector_type(4)));

#define C_   128
#define N_   4096
#define NH_  8
#define HD_  16
#define FF_  2048
#define SCALE_Q 0.360673760222241f   // 0.25 * log2(e); attn uses v_exp_f32 (2^x)

__device__ __forceinline__ unsigned short f2bf_bits(float f) {
    bf16 h = __float2bfloat16(f);
    return *reinterpret_cast<unsigned short*>(&h);
}
// truncation-mode bf16 pack: single v_perm_b32. Bit-identical to (hi&0xffff0000)|(lo>>16).
__device__ __forceinline__ unsigned int pack_trunc(float lo, float hi) {
    return __builtin_amdgcn_perm(__float_as_uint(hi), __float_as_uint(lo), 0x07060302u);
}
__device__ __forceinline__ short f2bf_trunc(float f) {
    return (short)(__float_as_uint(f) >> 16);
}
__device__ __forceinline__ float bfs2f(short s) {
    return __uint_as_float(((unsigned int)(unsigned short)s) << 16);
}
__device__ __forceinline__ float fast_exp2(float x) {
    return __builtin_amdgcn_exp2f(x);
}
__device__ __forceinline__ f32x4 mfma16(short8 a, short8 b, f32x4 c) {
    return __builtin_amdgcn_mfma_f32_16x16x32_bf16(a, b, c, 0, 0, 0);
}

// ---------------- K0: prep — vectorized; R18: NT stores (avoid remote-dirty L2 lines) ----
// R17 measurement: consumers of these buffers stall on cross-XCD dirty-line reads.
// NT stores keep the lines out of the producer XCD's L2 so consumer misses are clean.
__global__ void __launch_bounds__(256) k_prep(
    const float* __restrict__ Wq, const float* __restrict__ Wk,
    const float* __restrict__ Wv, const float* __restrict__ Wo,
    const float* __restrict__ W1, const float* __restrict__ W2,
    const float* __restrict__ x,
    bf16* __restrict__ Wqkvf, bf16* __restrict__ Wof,
    bf16* __restrict__ W1f, bf16* __restrict__ W2f,
    bf16* __restrict__ xTf)
{
    const int i = blockIdx.x * 256 + threadIdx.x;   // [0, 139264)
    if (i < 73728) {
        const float* row;
        bf16* dst;
        int kblk, g;
        if (i < 8192) {                      // QKV (o 0..383) + Wo (o 384..511), K=128
            const int o = i >> 4;
            kblk = (i >> 2) & 3; g = i & 3;
            const int odx = (o < 384) ? o : o - 384;
            row = (o < 128) ? (Wq + o * 128)
                : (o < 256) ? (Wk + (o - 128) * 128)
                : (o < 384) ? (Wv + (o - 256) * 128)
                            : (Wo + (o - 384) * 128);
            bf16* buf = (o < 384) ? Wqkvf : Wof;
            dst = buf + ((((odx >> 4) << 2) + kblk) * 512 + ((g << 4) + (odx & 15)) * 8);
        } else if (i < 40960) {              // W1 : [2048][128]
            const int t = i - 8192, o = t >> 4;
            kblk = (t >> 2) & 3; g = t & 3;
            row = W1 + o * 128;
            dst = W1f + ((((o >> 4) << 2) + kblk) * 512 + ((g << 4) + (o & 15)) * 8);
        } else {                             // W2 : [128][2048]
            const int t = i - 40960, o = t >> 8;
            kblk = (t >> 2) & 63; g = t & 3;
            row = W2 + o * 2048;
            dst = W2f + ((((o >> 4) << 6) + kblk) * 512 + ((g << 4) + (o & 15)) * 8);
        }
        const int k0 = kblk * 32 + g * 4;
        const f32x4 lo = *(const f32x4*)(row + k0);
        const f32x4 hi = *(const f32x4*)(row + k0 + 16);
        u32x4 w;
        #pragma unroll
        for (int j = 0; j < 4; ++j)
            w[j] = ((unsigned int)f2bf_bits(hi[j]) << 16) | f2bf_bits(lo[j]);
        __builtin_nontemporal_store(w, (u32x4*)dst);
    } else {                                 // x : [128][4096] -> xTf A-frags (transpose)
        const int t = i - 73728;             // [0, 65536)
        const int n = t & 4095, g = (t >> 12) & 3, cblk = t >> 14;
        const int c0 = cblk * 32 + g * 4;
        const float* xs = x + (size_t)c0 * 4096 + n;
        u32x4 w;
        #pragma unroll
        for (int j = 0; j < 4; ++j)
            w[j] = ((unsigned int)f2bf_bits(xs[(size_t)(16 + j) * 4096]) << 16)
                 | f2bf_bits(xs[(size_t)j * 4096]);
        bf16* dst = xTf + ((((n >> 4) << 2) + cblk) * 512 + ((g << 4) + (n & 15)) * 8);
        __builtin_nontemporal_store(w, (u32x4*)dst);
    }
}

// ---------------- K1: QKV — barrier-free fragment-streaming GEMM; R18: NT stores --------
__global__ void __launch_bounds__(256) k_qkv(
    const bf16* __restrict__ xTf, const bf16* __restrict__ Wqkvf,
    const float* __restrict__ bq, const float* __restrict__ bk, const float* __restrict__ bv,
    bf16* __restrict__ qf, bf16* __restrict__ kf, bf16* __restrict__ vf)
{
    const int tid = threadIdx.x, wave = tid >> 6, lane = tid & 63;
    const int col = lane & 15, quad = lane >> 4;
    const int gw = blockIdx.x * 4 + wave;     // [0, 6144)
    const int rt = gw / 24, ct = gw % 24;
    f32x4 acc = {};
    #pragma unroll
    for (int c = 0; c < 4; ++c) {
        short8 a = *(const short8*)(xTf + ((size_t)(rt * 4 + c) << 9) + lane * 8);
        short8 b = *(const short8*)(Wqkvf + ((size_t)(ct * 4 + c) << 9) + lane * 8);
        acc = mfma16(a, b, acc);
    }
    #pragma unroll
    for (int r = 0; r < 4; ++r) {
        const int m = rt * 16 + quad * 4 + r;
        const int n = ct * 16 + col;
        const float v = acc[r];
        if (n < 128) {
            const int h = n >> 4, ch = n & 15;
            __builtin_nontemporal_store(
                f2bf_bits((v + bq[n]) * SCALE_Q),
                (unsigned short*)(qf + ((h << 8) + (m >> 4)) * 256
                                     + (((ch >> 3) << 4) + (m & 15)) * 8 + (ch & 7)));
        } else if (n < 256) {
            const int c2 = n - 128, h = c2 >> 4, ch = c2 & 15;
            __builtin_nontemporal_store(
                f2bf_bits(v + bk[c2]),
                (unsigned short*)(kf + ((h << 8) + (m >> 4)) * 256
                                     + (((ch >> 3) << 4) + (m & 15)) * 8 + (ch & 7)));
        } else {
            const int c2 = n - 256, h = c2 >> 4, ch = c2 & 15;
            const int ko = m & 31;
            const int pos = ((ko & 15) << 1) + (ko >> 4);
            __builtin_nontemporal_store(
                f2bf_bits(v + bv[c2]),
                (unsigned short*)(vf + ((h << 7) + (m >> 5)) * 512
                                     + (((pos >> 3) << 4) + ch) * 8 + (pos & 7)));
        }
    }
}

// ---------------- K2: MFMA flash attention — q-tile grouping (R14); R18: NT af store ----
__global__ void __launch_bounds__(256)
attn_kernel(const bf16* __restrict__ qf, const bf16* __restrict__ kf,
            const bf16* __restrict__ vf, bf16* __restrict__ af)
{
    __shared__ __align__(16) union {
        unsigned int P[4][4][2][320];   // [wave][qt][buf] transpose bufs, 40 KB
        float comb[4][4][64][8];        // [qt][wave][lane][O0..3,L0..3], 32 KB
    } sh;
    const int tid = threadIdx.x, wave = tid >> 6, lane = tid & 63;
    const int col = lane & 15, quad = lane >> 4;
    const int gw = blockIdx.x;                   // [0, 512)
    const int h  = gw >> 6;
    const int tile0 = (gw & 63) << 2;
    const f32x4 zero = {};

    short8 aq[4] = {{}, {}, {}, {}};
    if (quad < 2) {
        #pragma unroll
        for (int qt = 0; qt < 4; ++qt)
            aq[qt] = *(const short8*)(qf + ((size_t)((h << 8) + tile0 + qt) << 8) + lane * 8);
    }

    const short8 onesb = { (short)0x3F80, (short)0x3F80, (short)0x3F80, (short)0x3F80,
                           (short)0x3F80, (short)0x3F80, (short)0x3F80, (short)0x3F80 };

    f32x4 accO[4] = {{}, {}, {}, {}};
    f32x4 accL[4] = {{}, {}, {}, {}};

    const int kbeg = wave << 10;

    for (int i = 0; i < 32; i += 2) {
        const int mA = kbeg + (i << 5);
        const int mB = mA + 32;

        short8 bkA0 = {}, bkA1 = {}, bkB0 = {}, bkB1 = {};
        if (quad < 2) {
            const bf16* ka = kf + ((size_t)((h << 8) + (mA >> 4)) << 8) + lane * 8;
            bkA0 = *(const short8*)(ka);
            bkA1 = *(const short8*)(ka + 256);
            bkB0 = *(const short8*)(ka + 512);
            bkB1 = *(const short8*)(ka + 768);
        }
        const short8 vA = *(const short8*)(vf + ((size_t)((h << 7) + (mA >> 5)) << 9) + lane * 8);
        const short8 vB = *(const short8*)(vf + ((size_t)((h << 7) + (mB >> 5)) << 9) + lane * 8);

        #pragma unroll
        for (int qt = 0; qt < 4; ++qt) {
            f32x4 s0 = mfma16(aq[qt], bkA0, zero);
            f32x4 s1 = mfma16(aq[qt], bkA1, zero);
            f32x4 s2 = mfma16(aq[qt], bkB0, zero);
            f32x4 s3 = mfma16(aq[qt], bkB1, zero);
            unsigned int* P0 = &sh.P[wave][qt][0][0];
            unsigned int* P1 = &sh.P[wave][qt][1][0];
            #pragma unroll
            for (int r = 0; r < 4; ++r) {
                P0[(quad * 4 + r) * 20 + col] = pack_trunc(fast_exp2(s0[r]), fast_exp2(s1[r]));
                P1[(quad * 4 + r) * 20 + col] = pack_trunc(fast_exp2(s2[r]), fast_exp2(s3[r]));
            }
        }
        #pragma unroll
        for (int qt = 0; qt < 4; ++qt) {
            const short* Ps0 = (const short*)&sh.P[wave][qt][0][0];
            const short* Ps1 = (const short*)&sh.P[wave][qt][1][0];
            short8 ap0 = *(const short8*)(Ps0 + col * 40 + quad * 8);
            accO[qt] = mfma16(ap0, vA, accO[qt]);
            accL[qt] = mfma16(ap0, onesb, accL[qt]);
            short8 ap1 = *(const short8*)(Ps1 + col * 40 + quad * 8);
            accO[qt] = mfma16(ap1, vB, accO[qt]);
            accL[qt] = mfma16(ap1, onesb, accL[qt]);
        }
    }

    __syncthreads();
    #pragma unroll
    for (int qt = 0; qt < 4; ++qt)
        #pragma unroll
        for (int r = 0; r < 4; ++r) {
            sh.comb[qt][wave][lane][r]     = accO[qt][r];
            sh.comb[qt][wave][lane][4 + r] = accL[qt][r];
        }
    __syncthreads();

    {   // wave w finalizes q-tile w
        const int qt = wave, tile = tile0 + qt;
        #pragma unroll
        for (int r = 0; r < 4; ++r) {
            float O = sh.comb[qt][0][lane][r] + sh.comb[qt][1][lane][r]
                    + sh.comb[qt][2][lane][r] + sh.comb[qt][3][lane][r];
            float l = sh.comb[qt][0][lane][4+r] + sh.comb[qt][1][lane][4+r]
                    + sh.comb[qt][2][lane][4+r] + sh.comb[qt][3][lane][4+r];
            const int row16 = quad * 4 + r;
            const int pk = (col << 1) + (h & 1);
            __builtin_nontemporal_store(
                f2bf_bits(O / l),
                (unsigned short*)(af + ((tile << 2) + (h >> 1)) * 512
                                     + (((pk >> 3) << 4) + row16) * 8 + (pk & 7)));
        }
    }
}

// ---------------- K3: MEGA — 8 waves; R18: FFN loop fully unrolled (load pipelining) ----
// R17 counters: MfmaUtil 1.9%, VALUBusy 2.1% -> memory-side stalls dominate. Unrolling
// gives compile-time ffc so the scheduler hoists chunk i+1's W1/W2 global loads above
// chunk i's LDS pack->read round-trip (Pb is double-buffered; per-thread LDS aliasing
// keeps DS order). launch_bounds(512,2) bounds VGPR growth at 256.
__global__ void __launch_bounds__(512, 2)
k_mega(const bf16* __restrict__ af, const bf16* __restrict__ xTf,
       const bf16* __restrict__ Wof, const bf16* __restrict__ W1f, const bf16* __restrict__ W2f,
       const float* __restrict__ bo, const float* __restrict__ b1, const float* __restrict__ b2,
       const float* __restrict__ g1, const float* __restrict__ be1,
       const float* __restrict__ g2, const float* __restrict__ be2,
       float* __restrict__ out)
{
    __shared__ __align__(16) unsigned int Pb[8][2][320];   // per-wave transpose dbuf (20 KB)
    __shared__ float comb[224][64];                         // ffn2 partials, waves 1-7 (56 KB)
    const int tid = threadIdx.x, wave = tid >> 6, lane = tid & 63;
    const int col = lane & 15, quad = lane >> 4;
    const int rt = blockIdx.x, n0 = rt << 4;
    const f32x4 zero = {};

    // ---- oproj: D = attn_frag . Wo^T  (each wave redundantly; 32 MFMA, cheap) ----
    short8 ao[4], xt[4];
    #pragma unroll
    for (int c = 0; c < 4; ++c) {
        ao[c] = *(const short8*)(af  + ((size_t)(rt * 4 + c) << 9) + lane * 8);
        xt[c] = *(const short8*)(xTf + ((size_t)(rt * 4 + c) << 9) + lane * 8);
    }
    f32x4 d[8];
    #pragma unroll
    for (int t = 0; t < 8; ++t) d[t] = zero;
    #pragma unroll
    for (int t = 0; t < 8; ++t)
        #pragma unroll
        for (int c = 0; c < 4; ++c) {
            short8 b = *(const short8*)(Wof + ((size_t)(t * 4 + c) << 9) + lane * 8);
            d[t] = mfma16(ao[c], b, d[t]);
        }
    #pragma unroll
    for (int t = 0; t < 8; ++t) {
        const float bt = bo[t * 16 + col];
        #pragma unroll
        for (int r = 0; r < 4; ++r) d[t][r] += bt;
    }

    // ---- D->A transpose via wave-private LDS; add residual x ----
    float x1f[4][8];
    #pragma unroll
    for (int c = 0; c < 4; ++c) {
        unsigned int* Pw = &Pb[wave][c & 1][0];
        const short* Ps = (const short*)Pw;
        #pragma unroll
        for (int r = 0; r < 4; ++r)
            Pw[(quad * 4 + r) * 20 + col] = pack_trunc(d[2 * c][r], d[2 * c + 1][r]);
        short8 ar = *(const short8*)(Ps + col * 40 + quad * 8);
        #pragma unroll
        for (int j = 0; j < 8; ++j)
            x1f[c][j] = bfs2f(ar[j]) + bfs2f(xt[c][j]);
    }

    // ---- LN1 (redundant in every wave; shfl-only) ----
    float s = 0.f, ss = 0.f;
    #pragma unroll
    for (int c = 0; c < 4; ++c)
        #pragma unroll
        for (int j = 0; j < 8; ++j) { s += x1f[c][j]; ss += x1f[c][j] * x1f[c][j]; }
    s  += __shfl_xor(s, 16);  s  += __shfl_xor(s, 32);
    ss += __shfl_xor(ss, 16); ss += __shfl_xor(ss, 32);
    const float m1 = s * (1.f / 128.f);
    const float rstd1 = rsqrtf(ss * (1.f / 128.f) - m1 * m1 + 1e-5f);
    short8 aq1[4];
    #pragma unroll
    for (int c = 0; c < 4; ++c)
        #pragma unroll
        for (int j = 0; j < 8; ++j) {
            const int pos = quad * 8 + j;
            const int ko = ((pos & 1) << 4) + (pos >> 1);
            const int ch = c * 32 + ko;
            aq1[c][j] = f2bf_trunc((x1f[c][j] - m1) * rstd1 * g1[ch] + be1[ch]);
        }

    // ---- FFN: this wave owns FF range [wave*256, +256) = 8 chunks of 32 ----
    f32x4 ACC[8];
    #pragma unroll
    for (int t = 0; t < 8; ++t) ACC[t] = zero;
    #pragma unroll
    for (int i = 0; i < 8; ++i) {
        const int ffc = (wave << 3) + i;                  // global 32-FF chunk [0,64)
        f32x4 p0 = zero, p1 = zero;
        #pragma unroll
        for (int c = 0; c < 4; ++c) {
            short8 b = *(const short8*)(W1f + ((size_t)(ffc * 8 + c) << 9) + lane * 8);
            p0 = mfma16(aq1[c], b, p0);
        }
        #pragma unroll
        for (int c = 0; c < 4; ++c) {
            short8 b = *(const short8*)(W1f + ((size_t)(ffc * 8 + 4 + c) << 9) + lane * 8);
            p1 = mfma16(aq1[c], b, p1);
        }
        const float bb0 = b1[ffc * 32 + col], bb1 = b1[ffc * 32 + 16 + col];
        unsigned int* Pw = &Pb[wave][i & 1][0];
        #pragma unroll
        for (int r = 0; r < 4; ++r)
            Pw[(quad * 4 + r) * 20 + col] =
                pack_trunc(fmaxf(p0[r] + bb0, 0.f), fmaxf(p1[r] + bb1, 0.f));
        short8 ah = *(const short8*)((const short*)Pw + col * 40 + quad * 8);
        #pragma unroll
        for (int t = 0; t < 8; ++t) {
            short8 bw = *(const short8*)(W2f + ((size_t)(t * 64 + ffc) << 9) + lane * 8);
            ACC[t] = mfma16(ah, bw, ACC[t]);
        }
    }

    // ---- tree-combine ffn2 partials; wave0: residual + LN2 + store ----
    if (wave) {
        #pragma unroll
        for (int t = 0; t < 8; ++t)
            #pragma unroll
            for (int r = 0; r < 4; ++r)
                comb[(wave - 1) * 32 + t * 4 + r][lane] = ACC[t][r];
    }
    __syncthreads();
    if (wave == 0) {
        #pragma unroll
        for (int t = 0; t < 8; ++t)
            #pragma unroll
            for (int r = 0; r < 4; ++r) {
                float acc = ACC[t][r];
                #pragma unroll
                for (int w = 0; w < 7; ++w)
                    acc += comb[w * 32 + t * 4 + r][lane];
                ACC[t][r] = acc;
            }
        short* xb = (short*)&Pb[0][0][0];   // [row16][chunk][32 pk] = 4096 shorts
        #pragma unroll
        for (int c = 0; c < 4; ++c)
            *(short8*)(xb + (col * 4 + c) * 32 + quad * 8) = aq1[c];
        float t2[8][4];
        #pragma unroll
        for (int t = 0; t < 8; ++t) {
            const int ch = t * 16 + col;
            const int pk = (col << 1) + (t & 1);
            const int c = t >> 1;
            const float bb = b2[ch];
            #pragma unroll
            for (int r = 0; r < 4; ++r)
                t2[t][r] = ACC[t][r] + bb + bfs2f(xb[((quad * 4 + r) * 4 + c) * 32 + pk]);
        }
        #pragma unroll
        for (int r = 0; r < 4; ++r) {
            float S = 0.f, SS = 0.f;
            #pragma unroll
            for (int t = 0; t < 8; ++t) { S += t2[t][r]; SS += t2[t][r] * t2[t][r]; }
            S  += __shfl_xor(S, 1);  S  += __shfl_xor(S, 2);
            S  += __shfl_xor(S, 4);  S  += __shfl_xor(S, 8);
            SS += __shfl_xor(SS, 1); SS += __shfl_xor(SS, 2);
            SS += __shfl_xor(SS, 4); SS += __shfl_xor(SS, 8);
            const float m2 = S * (1.f / 128.f);
            const float rstd2 = rsqrtf(SS * (1.f / 128.f) - m2 * m2 + 1e-5f);
            #pragma unroll
            for (int t = 0; t < 8; ++t) {
                const int ch = t * 16 + col;
                __builtin_nontemporal_store(
                    (t2[t][r] - m2) * rstd2 * g2[ch] + be2[ch],
                    out + (size_t)ch * N_ + n0 + quad * 4 + r);
            }
        }
    }
}

extern "C" void kernel_launch(void* const* d_in, const int* in_sizes, int n_in,
                              void* d_out, int out_size, void* d_ws, size_t ws_size,
                              hipStream_t stream) {
    const float* x   = (const float*)d_in[0];
    const float* Wq  = (const float*)d_in[1];
    const float* bq  = (const float*)d_in[2];
    const float* Wk  = (const float*)d_in[3];
    const float* bk  = (const float*)d_in[4];
    const float* Wv  = (const float*)d_in[5];
    const float* bv  = (const float*)d_in[6];
    const float* Wo  = (const float*)d_in[7];
    const float* bo  = (const float*)d_in[8];
    const float* W1  = (const float*)d_in[9];
    const float* b1  = (const float*)d_in[10];
    const float* W2  = (const float*)d_in[11];
    const float* b2  = (const float*)d_in[12];
    const float* g1  = (const float*)d_in[13];
    const float* be1 = (const float*)d_in[14];
    const float* g2  = (const float*)d_in[15];
    const float* be2 = (const float*)d_in[16];
    float* out = (float*)d_out;

    char* ws = (char*)d_ws;
    bf16* xTf   = (bf16*)(ws + 0);          // 1 MB
    bf16* qf    = (bf16*)(ws + 1048576);    // 1 MB
    bf16* kf    = (bf16*)(ws + 2097152);    // 1 MB
    bf16* vf    = (bf16*)(ws + 3145728);    // 1 MB
    bf16* af    = (bf16*)(ws + 4194304);    // 1 MB
    bf16* Wqkvf = (bf16*)(ws + 5242880);    // 96 KB
    bf16* Wof   = (bf16*)(ws + 5341184);    // 32 KB
    bf16* W1f   = (bf16*)(ws + 5373952);    // 512 KB
    bf16* W2f   = (bf16*)(ws + 5898240);    // 512 KB

    k_prep<<<544, 256, 0, stream>>>(Wq, Wk, Wv, Wo, W1, W2, x, Wqkvf, Wof, W1f, W2f, xTf);
    k_qkv<<<1536, 256, 0, stream>>>(xTf, Wqkvf, bq, bk, bv, qf, kf, vf);
    attn_kernel<<<512, 256, 0, stream>>>(qf, kf, vf, af);
    k_mega<<<256, 512, 0, stream>>>(af, xTf, Wof, W1f, W2f, bo, b1, b2,
                                    g1, be1, g2, be2, out);
}

// Round 8
// 141.991 us; speedup vs baseline: 8.5659x; 1.0482x over previous
//
#include <hip/hip_runtime.h>
#include <hip/hip_bf16.h>

typedef __hip_bfloat16 bf16;
typedef short short8 __attribute__((ext_vector_type(8)));
typedef float f32x4 __attribute__((ext_vector_type(4)));
typedef unsigned int u32x4 __attribute__((ext_vector_type(4)));

#define C_   128
#define N_   4096
#define NH_  8
#define HD_  16
#define FF_  2048
#define SCALE_Q 0.360673760222241f   // 0.25 * log2(e); attn uses v_exp_f32 (2^x)

__device__ __forceinline__ unsigned short f2bf_bits(float f) {
    bf16 h = __float2bfloat16(f);
    return *reinterpret_cast<unsigned short*>(&h);
}
// truncation-mode bf16 pack: single v_perm_b32. Bit-identical to (hi&0xffff0000)|(lo>>16).
__device__ __forceinline__ unsigned int pack_trunc(float lo, float hi) {
    return __builtin_amdgcn_perm(__float_as_uint(hi), __float_as_uint(lo), 0x07060302u);
}
__device__ __forceinline__ short f2bf_trunc(float f) {
    return (short)(__float_as_uint(f) >> 16);
}
__device__ __forceinline__ float bfs2f(short s) {
    return __uint_as_float(((unsigned int)(unsigned short)s) << 16);
}
__device__ __forceinline__ float fast_exp2(float x) {
    return __builtin_amdgcn_exp2f(x);
}
__device__ __forceinline__ f32x4 mfma16(short8 a, short8 b, f32x4 c) {
    return __builtin_amdgcn_mfma_f32_16x16x32_bf16(a, b, c, 0, 0, 0);
}

// ---------------- K0: prep — vectorized: one short8 (16B) store per thread (R14) --------
__global__ void __launch_bounds__(256) k_prep(
    const float* __restrict__ Wq, const float* __restrict__ Wk,
    const float* __restrict__ Wv, const float* __restrict__ Wo,
    const float* __restrict__ W1, const float* __restrict__ W2,
    const float* __restrict__ x,
    bf16* __restrict__ Wqkvf, bf16* __restrict__ Wof,
    bf16* __restrict__ W1f, bf16* __restrict__ W2f,
    bf16* __restrict__ xTf)
{
    const int i = blockIdx.x * 256 + threadIdx.x;   // [0, 139264)
    if (i < 73728) {
        const float* row;
        bf16* dst;
        int kblk, g;
        if (i < 8192) {                      // QKV (o 0..383) + Wo (o 384..511), K=128
            const int o = i >> 4;
            kblk = (i >> 2) & 3; g = i & 3;
            const int odx = (o < 384) ? o : o - 384;
            row = (o < 128) ? (Wq + o * 128)
                : (o < 256) ? (Wk + (o - 128) * 128)
                : (o < 384) ? (Wv + (o - 256) * 128)
                            : (Wo + (o - 384) * 128);
            bf16* buf = (o < 384) ? Wqkvf : Wof;
            dst = buf + ((((odx >> 4) << 2) + kblk) * 512 + ((g << 4) + (odx & 15)) * 8);
        } else if (i < 40960) {              // W1 : [2048][128]
            const int t = i - 8192, o = t >> 4;
            kblk = (t >> 2) & 3; g = t & 3;
            row = W1 + o * 128;
            dst = W1f + ((((o >> 4) << 2) + kblk) * 512 + ((g << 4) + (o & 15)) * 8);
        } else {                             // W2 : [128][2048]
            const int t = i - 40960, o = t >> 8;
            kblk = (t >> 2) & 63; g = t & 3;
            row = W2 + o * 2048;
            dst = W2f + ((((o >> 4) << 6) + kblk) * 512 + ((g << 4) + (o & 15)) * 8);
        }
        const int k0 = kblk * 32 + g * 4;
        const f32x4 lo = *(const f32x4*)(row + k0);
        const f32x4 hi = *(const f32x4*)(row + k0 + 16);
        u32x4 w;
        #pragma unroll
        for (int j = 0; j < 4; ++j)
            w[j] = ((unsigned int)f2bf_bits(hi[j]) << 16) | f2bf_bits(lo[j]);
        *(u32x4*)dst = w;
    } else {                                 // x : [128][4096] -> xTf A-frags (transpose)
        const int t = i - 73728;             // [0, 65536)
        const int n = t & 4095, g = (t >> 12) & 3, cblk = t >> 14;
        const int c0 = cblk * 32 + g * 4;
        const float* xs = x + (size_t)c0 * 4096 + n;
        u32x4 w;
        #pragma unroll
        for (int j = 0; j < 4; ++j)
            w[j] = ((unsigned int)f2bf_bits(xs[(size_t)(16 + j) * 4096]) << 16)
                 | f2bf_bits(xs[(size_t)j * 4096]);
        bf16* dst = xTf + ((((n >> 4) << 2) + cblk) * 512 + ((g << 4) + (n & 15)) * 8);
        *(u32x4*)dst = w;
    }
}

// ---------------- K1: QKV — barrier-free fragment-streaming GEMM (R14) ----------------
__global__ void __launch_bounds__(256) k_qkv(
    const bf16* __restrict__ xTf, const bf16* __restrict__ Wqkvf,
    const float* __restrict__ bq, const float* __restrict__ bk, const float* __restrict__ bv,
    bf16* __restrict__ qf, bf16* __restrict__ kf, bf16* __restrict__ vf)
{
    const int tid = threadIdx.x, wave = tid >> 6, lane = tid & 63;
    const int col = lane & 15, quad = lane >> 4;
    const int gw = blockIdx.x * 4 + wave;     // [0, 6144)
    const int rt = gw / 24, ct = gw % 24;
    f32x4 acc = {};
    #pragma unroll
    for (int c = 0; c < 4; ++c) {
        short8 a = *(const short8*)(xTf + ((size_t)(rt * 4 + c) << 9) + lane * 8);
        short8 b = *(const short8*)(Wqkvf + ((size_t)(ct * 4 + c) << 9) + lane * 8);
        acc = mfma16(a, b, acc);
    }
    #pragma unroll
    for (int r = 0; r < 4; ++r) {
        const int m = rt * 16 + quad * 4 + r;
        const int n = ct * 16 + col;
        const float v = acc[r];
        if (n < 128) {
            const int h = n >> 4, ch = n & 15;
            qf[((h << 8) + (m >> 4)) * 256 + (((ch >> 3) << 4) + (m & 15)) * 8 + (ch & 7)] =
                __float2bfloat16((v + bq[n]) * SCALE_Q);
        } else if (n < 256) {
            const int c2 = n - 128, h = c2 >> 4, ch = c2 & 15;
            kf[((h << 8) + (m >> 4)) * 256 + (((ch >> 3) << 4) + (m & 15)) * 8 + (ch & 7)] =
                __float2bfloat16(v + bk[c2]);
        } else {
            const int c2 = n - 256, h = c2 >> 4, ch = c2 & 15;
            const int ko = m & 31;
            const int pos = ((ko & 15) << 1) + (ko >> 4);
            vf[((h << 7) + (m >> 5)) * 512 + (((pos >> 3) << 4) + ch) * 8 + (pos & 7)] =
                __float2bfloat16(v + bv[c2]);
        }
    }
}

// ---------------- K2: MFMA flash attention — q-tile grouping for KV L2 reuse (R14) ------
__global__ void __launch_bounds__(256)
attn_kernel(const bf16* __restrict__ qf, const bf16* __restrict__ kf,
            const bf16* __restrict__ vf, bf16* __restrict__ af)
{
    __shared__ __align__(16) union {
        unsigned int P[4][4][2][320];   // [wave][qt][buf] transpose bufs, 40 KB
        float comb[4][4][64][8];        // [qt][wave][lane][O0..3,L0..3], 32 KB
    } sh;
    const int tid = threadIdx.x, wave = tid >> 6, lane = tid & 63;
    const int col = lane & 15, quad = lane >> 4;
    const int gw = blockIdx.x;                   // [0, 512)
    const int h  = gw >> 6;
    const int tile0 = (gw & 63) << 2;
    const f32x4 zero = {};

    short8 aq[4] = {{}, {}, {}, {}};
    if (quad < 2) {
        #pragma unroll
        for (int qt = 0; qt < 4; ++qt)
            aq[qt] = *(const short8*)(qf + ((size_t)((h << 8) + tile0 + qt) << 8) + lane * 8);
    }

    const short8 onesb = { (short)0x3F80, (short)0x3F80, (short)0x3F80, (short)0x3F80,
                           (short)0x3F80, (short)0x3F80, (short)0x3F80, (short)0x3F80 };

    f32x4 accO[4] = {{}, {}, {}, {}};
    f32x4 accL[4] = {{}, {}, {}, {}};

    const int kbeg = wave << 10;

    for (int i = 0; i < 32; i += 2) {
        const int mA = kbeg + (i << 5);
        const int mB = mA + 32;

        short8 bkA0 = {}, bkA1 = {}, bkB0 = {}, bkB1 = {};
        if (quad < 2) {
            const bf16* ka = kf + ((size_t)((h << 8) + (mA >> 4)) << 8) + lane * 8;
            bkA0 = *(const short8*)(ka);
            bkA1 = *(const short8*)(ka + 256);
            bkB0 = *(const short8*)(ka + 512);
            bkB1 = *(const short8*)(ka + 768);
        }
        const short8 vA = *(const short8*)(vf + ((size_t)((h << 7) + (mA >> 5)) << 9) + lane * 8);
        const short8 vB = *(const short8*)(vf + ((size_t)((h << 7) + (mB >> 5)) << 9) + lane * 8);

        #pragma unroll
        for (int qt = 0; qt < 4; ++qt) {
            f32x4 s0 = mfma16(aq[qt], bkA0, zero);
            f32x4 s1 = mfma16(aq[qt], bkA1, zero);
            f32x4 s2 = mfma16(aq[qt], bkB0, zero);
            f32x4 s3 = mfma16(aq[qt], bkB1, zero);
            unsigned int* P0 = &sh.P[wave][qt][0][0];
            unsigned int* P1 = &sh.P[wave][qt][1][0];
            #pragma unroll
            for (int r = 0; r < 4; ++r) {
                P0[(quad * 4 + r) * 20 + col] = pack_trunc(fast_exp2(s0[r]), fast_exp2(s1[r]));
                P1[(quad * 4 + r) * 20 + col] = pack_trunc(fast_exp2(s2[r]), fast_exp2(s3[r]));
            }
        }
        #pragma unroll
        for (int qt = 0; qt < 4; ++qt) {
            const short* Ps0 = (const short*)&sh.P[wave][qt][0][0];
            const short* Ps1 = (const short*)&sh.P[wave][qt][1][0];
            short8 ap0 = *(const short8*)(Ps0 + col * 40 + quad * 8);
            accO[qt] = mfma16(ap0, vA, accO[qt]);
            accL[qt] = mfma16(ap0, onesb, accL[qt]);
            short8 ap1 = *(const short8*)(Ps1 + col * 40 + quad * 8);
            accO[qt] = mfma16(ap1, vB, accO[qt]);
            accL[qt] = mfma16(ap1, onesb, accL[qt]);
        }
    }

    __syncthreads();
    #pragma unroll
    for (int qt = 0; qt < 4; ++qt)
        #pragma unroll
        for (int r = 0; r < 4; ++r) {
            sh.comb[qt][wave][lane][r]     = accO[qt][r];
            sh.comb[qt][wave][lane][4 + r] = accL[qt][r];
        }
    __syncthreads();

    {   // wave w finalizes q-tile w
        const int qt = wave, tile = tile0 + qt;
        #pragma unroll
        for (int r = 0; r < 4; ++r) {
            float O = sh.comb[qt][0][lane][r] + sh.comb[qt][1][lane][r]
                    + sh.comb[qt][2][lane][r] + sh.comb[qt][3][lane][r];
            float l = sh.comb[qt][0][lane][4+r] + sh.comb[qt][1][lane][4+r]
                    + sh.comb[qt][2][lane][4+r] + sh.comb[qt][3][lane][4+r];
            const int row16 = quad * 4 + r;
            const int pk = (col << 1) + (h & 1);
            af[((tile << 2) + (h >> 1)) * 512 + (((pk >> 3) << 4) + row16) * 8 + (pk & 7)] =
                __float2bfloat16(O / l);
        }
    }
}

// ---------------- K3: MEGA v2 — R19: 2 row-tiles/block, weight re-stream halved ---------
// R17 counters (MfmaUtil 1.9%, VALUBusy 2.1%, 172 MB/rep beyond-L2 fetch vs 5 MB unique):
// mega pays for the aggregate weight re-stream (256 blocks x 1.05 MB = 272 MB). This
// version: 128 blocks x 8 waves, each block owns 32 rows (2 row-tiles). Every W1/W2
// fragment is loaded once per block and consumed by TWO independent MFMA streams
// (rt0, rt1) -> aggregate stream 136 MB, MFMA:load ratio 2:1, and 16 blocks/XCD share
// one 1 MB stream in the 4 MB L2. FP summation order per output identical to R14
// (wave order 0..7) -> bit-identical results.
__global__ void __launch_bounds__(512)
k_mega(const bf16* __restrict__ af, const bf16* __restrict__ xTf,
       const bf16* __restrict__ Wof, const bf16* __restrict__ W1f, const bf16* __restrict__ W2f,
       const float* __restrict__ bo, const float* __restrict__ b1, const float* __restrict__ b2,
       const float* __restrict__ g1, const float* __restrict__ be1,
       const float* __restrict__ g2, const float* __restrict__ be2,
       float* __restrict__ out)
{
    __shared__ __align__(16) unsigned int Pb[8][2][320];   // per-wave transpose dbuf, 20 KB
    __shared__ __align__(16) short aqs[2][4][512];          // aq1 publish (rt0/rt1), 8 KB
    __shared__ float comb[7][64][64];                       // partials rt0 rows 0-31, rt1 32-63; 112 KB
    const int tid = threadIdx.x, wave = tid >> 6, lane = tid & 63;
    const int col = lane & 15, quad = lane >> 4;
    const int rtl = wave & 1;                               // this wave's oproj row-tile parity
    const int rt = (blockIdx.x << 1) + rtl;
    const f32x4 zero = {};

    // ---- oproj for this wave's rt (4 waves redundantly per rt; 32 MFMA, cheap) ----
    short8 ao[4], xt[4];
    #pragma unroll
    for (int c = 0; c < 4; ++c) {
        ao[c] = *(const short8*)(af  + ((size_t)(rt * 4 + c) << 9) + lane * 8);
        xt[c] = *(const short8*)(xTf + ((size_t)(rt * 4 + c) << 9) + lane * 8);
    }
    f32x4 d[8];
    #pragma unroll
    for (int t = 0; t < 8; ++t) d[t] = zero;
    #pragma unroll
    for (int t = 0; t < 8; ++t)
        #pragma unroll
        for (int c = 0; c < 4; ++c) {
            short8 b = *(const short8*)(Wof + ((size_t)(t * 4 + c) << 9) + lane * 8);
            d[t] = mfma16(ao[c], b, d[t]);
        }
    #pragma unroll
    for (int t = 0; t < 8; ++t) {
        const float bt = bo[t * 16 + col];
        #pragma unroll
        for (int r = 0; r < 4; ++r) d[t][r] += bt;
    }

    // ---- D->A transpose via wave-private LDS; add residual x ----
    float x1f[4][8];
    #pragma unroll
    for (int c = 0; c < 4; ++c) {
        unsigned int* Pw = &Pb[wave][c & 1][0];
        const short* Ps = (const short*)Pw;
        #pragma unroll
        for (int r = 0; r < 4; ++r)
            Pw[(quad * 4 + r) * 20 + col] = pack_trunc(d[2 * c][r], d[2 * c + 1][r]);
        short8 ar = *(const short8*)(Ps + col * 40 + quad * 8);
        #pragma unroll
        for (int j = 0; j < 8; ++j)
            x1f[c][j] = bfs2f(ar[j]) + bfs2f(xt[c][j]);
    }

    // ---- LN1 -> aq1 (this wave's rt) ----
    float s = 0.f, ss = 0.f;
    #pragma unroll
    for (int c = 0; c < 4; ++c)
        #pragma unroll
        for (int j = 0; j < 8; ++j) { s += x1f[c][j]; ss += x1f[c][j] * x1f[c][j]; }
    s  += __shfl_xor(s, 16);  s  += __shfl_xor(s, 32);
    ss += __shfl_xor(ss, 16); ss += __shfl_xor(ss, 32);
    const float m1 = s * (1.f / 128.f);
    const float rstd1 = rsqrtf(ss * (1.f / 128.f) - m1 * m1 + 1e-5f);
    short8 aq1[4];
    #pragma unroll
    for (int c = 0; c < 4; ++c)
        #pragma unroll
        for (int j = 0; j < 8; ++j) {
            const int pos = quad * 8 + j;
            const int ko = ((pos & 1) << 4) + (pos >> 1);
            const int ch = c * 32 + ko;
            aq1[c][j] = f2bf_trunc((x1f[c][j] - m1) * rstd1 * g1[ch] + be1[ch]);
        }

    // ---- publish aq1 so every wave holds BOTH rts in registers ----
    if (wave < 2) {
        #pragma unroll
        for (int c = 0; c < 4; ++c)
            *(short8*)&aqs[rtl][c][lane * 8] = aq1[c];
    }
    __syncthreads();
    short8 aqr0[4], aqr1[4];
    if (rtl == 0) {                       // wave-uniform branch
        #pragma unroll
        for (int c = 0; c < 4; ++c) {
            aqr0[c] = aq1[c];
            aqr1[c] = *(const short8*)&aqs[1][c][lane * 8];
        }
    } else {
        #pragma unroll
        for (int c = 0; c < 4; ++c) {
            aqr1[c] = aq1[c];
            aqr0[c] = *(const short8*)&aqs[0][c][lane * 8];
        }
    }

    // ---- FFN: wave owns 8 chunks of 32 FF; each W1/W2 frag feeds BOTH rts ----
    f32x4 ACC0[8], ACC1[8];
    #pragma unroll
    for (int t = 0; t < 8; ++t) { ACC0[t] = zero; ACC1[t] = zero; }
    #pragma unroll 2
    for (int i = 0; i < 8; ++i) {
        const int ffc = (wave << 3) + i;                  // global 32-FF chunk [0,64)
        short8 w1r[8];
        #pragma unroll
        for (int c = 0; c < 8; ++c)
            w1r[c] = *(const short8*)(W1f + ((size_t)(ffc * 8 + c) << 9) + lane * 8);
        const float bb0 = b1[ffc * 32 + col], bb1 = b1[ffc * 32 + 16 + col];
        // rt0 FFN1
        f32x4 p0 = zero, p1 = zero;
        #pragma unroll
        for (int c = 0; c < 4; ++c) p0 = mfma16(aqr0[c], w1r[c], p0);
        #pragma unroll
        for (int c = 0; c < 4; ++c) p1 = mfma16(aqr0[c], w1r[4 + c], p1);
        unsigned int* Pw0 = &Pb[wave][0][0];
        #pragma unroll
        for (int r = 0; r < 4; ++r)
            Pw0[(quad * 4 + r) * 20 + col] =
                pack_trunc(fmaxf(p0[r] + bb0, 0.f), fmaxf(p1[r] + bb1, 0.f));
        short8 ah0 = *(const short8*)((const short*)Pw0 + col * 40 + quad * 8);
        // rt1 FFN1
        f32x4 q0 = zero, q1 = zero;
        #pragma unroll
        for (int c = 0; c < 4; ++c) q0 = mfma16(aqr1[c], w1r[c], q0);
        #pragma unroll
        for (int c = 0; c < 4; ++c) q1 = mfma16(aqr1[c], w1r[4 + c], q1);
        unsigned int* Pw1 = &Pb[wave][1][0];
        #pragma unroll
        for (int r = 0; r < 4; ++r)
            Pw1[(quad * 4 + r) * 20 + col] =
                pack_trunc(fmaxf(q0[r] + bb0, 0.f), fmaxf(q1[r] + bb1, 0.f));
        short8 ah1 = *(const short8*)((const short*)Pw1 + col * 40 + quad * 8);
        // FFN2: one W2 frag, two MFMA streams
        #pragma unroll
        for (int t = 0; t < 8; ++t) {
            short8 bw = *(const short8*)(W2f + ((size_t)(t * 64 + ffc) << 9) + lane * 8);
            ACC0[t] = mfma16(ah0, bw, ACC0[t]);
            ACC1[t] = mfma16(ah1, bw, ACC1[t]);
        }
    }

    // ---- contribute partials (rt0 rows 0-31, rt1 rows 32-63) ----
    if (wave >= 1) {
        #pragma unroll
        for (int t = 0; t < 8; ++t)
            #pragma unroll
            for (int r = 0; r < 4; ++r)
                comb[wave - 1][t * 4 + r][lane] = ACC0[t][r];
    }
    if (wave != 1) {
        const int slot = (wave == 0) ? 0 : wave - 1;
        #pragma unroll
        for (int t = 0; t < 8; ++t)
            #pragma unroll
            for (int r = 0; r < 4; ++r)
                comb[slot][32 + t * 4 + r][lane] = ACC1[t][r];
    }
    __syncthreads();

    if (wave == 0) {                                      // finalize rt0 (= blk*2)
        const int n0 = rt << 4;                           // wave0: rt = blk*2
        #pragma unroll
        for (int t = 0; t < 8; ++t)
            #pragma unroll
            for (int r = 0; r < 4; ++r) {
                float a = ACC0[t][r];                     // own (wave0) first, then w1..w7
                #pragma unroll
                for (int w = 0; w < 7; ++w)
                    a += comb[w][t * 4 + r][lane];
                ACC0[t][r] = a;
            }
        short* xb = (short*)&Pb[0][0][0];                 // 8 KB scratch (Pb dead)
        #pragma unroll
        for (int c = 0; c < 4; ++c)
            *(short8*)(xb + (col * 4 + c) * 32 + quad * 8) = aq1[c];
        float t2[8][4];
        #pragma unroll
        for (int t = 0; t < 8; ++t) {
            const int ch = t * 16 + col;
            const int pk = (col << 1) + (t & 1);
            const int c = t >> 1;
            const float bb = b2[ch];
            #pragma unroll
            for (int r = 0; r < 4; ++r)
                t2[t][r] = ACC0[t][r] + bb + bfs2f(xb[((quad * 4 + r) * 4 + c) * 32 + pk]);
        }
        #pragma unroll
        for (int r = 0; r < 4; ++r) {
            float S = 0.f, SS = 0.f;
            #pragma unroll
            for (int t = 0; t < 8; ++t) { S += t2[t][r]; SS += t2[t][r] * t2[t][r]; }
            S  += __shfl_xor(S, 1);  S  += __shfl_xor(S, 2);
            S  += __shfl_xor(S, 4);  S  += __shfl_xor(S, 8);
            SS += __shfl_xor(SS, 1); SS += __shfl_xor(SS, 2);
            SS += __shfl_xor(SS, 4); SS += __shfl_xor(SS, 8);
            const float m2 = S * (1.f / 128.f);
            const float rstd2 = rsqrtf(SS * (1.f / 128.f) - m2 * m2 + 1e-5f);
            #pragma unroll
            for (int t = 0; t < 8; ++t) {
                const int ch = t * 16 + col;
                out[(size_t)ch * N_ + n0 + quad * 4 + r] =
                    (t2[t][r] - m2) * rstd2 * g2[ch] + be2[ch];
            }
        }
    }
    if (wave == 1) {                                      // finalize rt1 (= blk*2+1)
        const int n0 = rt << 4;                           // wave1: rt = blk*2+1
        #pragma unroll
        for (int t = 0; t < 8; ++t)
            #pragma unroll
            for (int r = 0; r < 4; ++r) {
                // order: w0 (slot0), own (wave1), then w2..w7 (slots 1..6)
                float a = comb[0][32 + t * 4 + r][lane] + ACC1[t][r];
                #pragma unroll
                for (int s2 = 1; s2 < 7; ++s2)
                    a += comb[s2][32 + t * 4 + r][lane];
                ACC1[t][r] = a;
            }
        short* xb = (short*)&Pb[4][0][0];                 // disjoint 8 KB scratch
        #pragma unroll
        for (int c = 0; c < 4; ++c)
            *(short8*)(xb + (col * 4 + c) * 32 + quad * 8) = aq1[c];
        float t2[8][4];
        #pragma unroll
        for (int t = 0; t < 8; ++t) {
            const int ch = t * 16 + col;
            const int pk = (col << 1) + (t & 1);
            const int c = t >> 1;
            const float bb = b2[ch];
            #pragma unroll
            for (int r = 0; r < 4; ++r)
                t2[t][r] = ACC1[t][r] + bb + bfs2f(xb[((quad * 4 + r) * 4 + c) * 32 + pk]);
        }
        #pragma unroll
        for (int r = 0; r < 4; ++r) {
            float S = 0.f, SS = 0.f;
            #pragma unroll
            for (int t = 0; t < 8; ++t) { S += t2[t][r]; SS += t2[t][r] * t2[t][r]; }
            S  += __shfl_xor(S, 1);  S  += __shfl_xor(S, 2);
            S  += __shfl_xor(S, 4);  S  += __shfl_xor(S, 8);
            SS += __shfl_xor(SS, 1); SS += __shfl_xor(SS, 2);
            SS += __shfl_xor(SS, 4); SS += __shfl_xor(SS, 8);
            const float m2 = S * (1.f / 128.f);
            const float rstd2 = rsqrtf(SS * (1.f / 128.f) - m2 * m2 + 1e-5f);
            #pragma unroll
            for (int t = 0; t < 8; ++t) {
                const int ch = t * 16 + col;
                out[(size_t)ch * N_ + n0 + quad * 4 + r] =
                    (t2[t][r] - m2) * rstd2 * g2[ch] + be2[ch];
            }
        }
    }
}

extern "C" void kernel_launch(void* const* d_in, const int* in_sizes, int n_in,
                              void* d_out, int out_size, void* d_ws, size_t ws_size,
                              hipStream_t stream) {
    const float* x   = (const float*)d_in[0];
    const float* Wq  = (const float*)d_in[1];
    const float* bq  = (const float*)d_in[2];
    const float* Wk  = (const float*)d_in[3];
    const float* bk  = (const float*)d_in[4];
    const float* Wv  = (const float*)d_in[5];
    const float* bv  = (const float*)d_in[6];
    const float* Wo  = (const float*)d_in[7];
    const float* bo  = (const float*)d_in[8];
    const float* W1  = (const float*)d_in[9];
    const float* b1  = (const float*)d_in[10];
    const float* W2  = (const float*)d_in[11];
    const float* b2  = (const float*)d_in[12];
    const float* g1  = (const float*)d_in[13];
    const float* be1 = (const float*)d_in[14];
    const float* g2  = (const float*)d_in[15];
    const float* be2 = (const float*)d_in[16];
    float* out = (float*)d_out;

    char* ws = (char*)d_ws;
    bf16* xTf   = (bf16*)(ws + 0);          // 1 MB
    bf16* qf    = (bf16*)(ws + 1048576);    // 1 MB
    bf16* kf    = (bf16*)(ws + 2097152);    // 1 MB
    bf16* vf    = (bf16*)(ws + 3145728);    // 1 MB
    bf16* af    = (bf16*)(ws + 4194304);    // 1 MB
    bf16* Wqkvf = (bf16*)(ws + 5242880);    // 96 KB
    bf16* Wof   = (bf16*)(ws + 5341184);    // 32 KB
    bf16* W1f   = (bf16*)(ws + 5373952);    // 512 KB
    bf16* W2f   = (bf16*)(ws + 5898240);    // 512 KB

    k_prep<<<544, 256, 0, stream>>>(Wq, Wk, Wv, Wo, W1, W2, x, Wqkvf, Wof, W1f, W2f, xTf);
    k_qkv<<<1536, 256, 0, stream>>>(xTf, Wqkvf, bq, bk, bv, qf, kf, vf);
    attn_kernel<<<512, 256, 0, stream>>>(qf, kf, vf, af);
    k_mega<<<128, 512, 0, stream>>>(af, xTf, Wof, W1f, W2f, bo, b1, b2,
                                    g1, be1, g2, be2, out);
}

// Round 9
// 140.173 us; speedup vs baseline: 8.6770x; 1.0130x over previous
//
#include <hip/hip_runtime.h>
#include <hip/hip_bf16.h>

typedef __hip_bfloat16 bf16;
typedef short short8 __attribute__((ext_vector_type(8)));
typedef float f32x4 __attribute__((ext_vector_type(4)));
typedef unsigned int u32x4 __attribute__((ext_vector_type(4)));

#define C_   128
#define N_   4096
#define NH_  8
#define HD_  16
#define FF_  2048
#define SCALE_Q 0.360673760222241f   // 0.25 * log2(e); attn uses v_exp_f32 (2^x)

__device__ __forceinline__ unsigned short f2bf_bits(float f) {
    bf16 h = __float2bfloat16(f);
    return *reinterpret_cast<unsigned short*>(&h);
}
// truncation-mode bf16 pack: single v_perm_b32. Bit-identical to (hi&0xffff0000)|(lo>>16).
__device__ __forceinline__ unsigned int pack_trunc(float lo, float hi) {
    return __builtin_amdgcn_perm(__float_as_uint(hi), __float_as_uint(lo), 0x07060302u);
}
__device__ __forceinline__ short f2bf_trunc(float f) {
    return (short)(__float_as_uint(f) >> 16);
}
__device__ __forceinline__ float bfs2f(short s) {
    return __uint_as_float(((unsigned int)(unsigned short)s) << 16);
}
__device__ __forceinline__ float fast_exp2(float x) {
    return __builtin_amdgcn_exp2f(x);
}
__device__ __forceinline__ f32x4 mfma16(short8 a, short8 b, f32x4 c) {
    return __builtin_amdgcn_mfma_f32_16x16x32_bf16(a, b, c, 0, 0, 0);
}

// ---------------- K0: prep — vectorized: one short8 (16B) store per thread (R14) --------
__global__ void __launch_bounds__(256) k_prep(
    const float* __restrict__ Wq, const float* __restrict__ Wk,
    const float* __restrict__ Wv, const float* __restrict__ Wo,
    const float* __restrict__ W1, const float* __restrict__ W2,
    const float* __restrict__ x,
    bf16* __restrict__ Wqkvf, bf16* __restrict__ Wof,
    bf16* __restrict__ W1f, bf16* __restrict__ W2f,
    bf16* __restrict__ xTf)
{
    const int i = blockIdx.x * 256 + threadIdx.x;   // [0, 139264)
    if (i < 73728) {
        const float* row;
        bf16* dst;
        int kblk, g;
        if (i < 8192) {                      // QKV (o 0..383) + Wo (o 384..511), K=128
            const int o = i >> 4;
            kblk = (i >> 2) & 3; g = i & 3;
            const int odx = (o < 384) ? o : o - 384;
            row = (o < 128) ? (Wq + o * 128)
                : (o < 256) ? (Wk + (o - 128) * 128)
                : (o < 384) ? (Wv + (o - 256) * 128)
                            : (Wo + (o - 384) * 128);
            bf16* buf = (o < 384) ? Wqkvf : Wof;
            dst = buf + ((((odx >> 4) << 2) + kblk) * 512 + ((g << 4) + (odx & 15)) * 8);
        } else if (i < 40960) {              // W1 : [2048][128]
            const int t = i - 8192, o = t >> 4;
            kblk = (t >> 2) & 3; g = t & 3;
            row = W1 + o * 128;
            dst = W1f + ((((o >> 4) << 2) + kblk) * 512 + ((g << 4) + (o & 15)) * 8);
        } else {                             // W2 : [128][2048]
            const int t = i - 40960, o = t >> 8;
            kblk = (t >> 2) & 63; g = t & 3;
            row = W2 + o * 2048;
            dst = W2f + ((((o >> 4) << 6) + kblk) * 512 + ((g << 4) + (o & 15)) * 8);
        }
        const int k0 = kblk * 32 + g * 4;
        const f32x4 lo = *(const f32x4*)(row + k0);
        const f32x4 hi = *(const f32x4*)(row + k0 + 16);
        u32x4 w;
        #pragma unroll
        for (int j = 0; j < 4; ++j)
            w[j] = ((unsigned int)f2bf_bits(hi[j]) << 16) | f2bf_bits(lo[j]);
        *(u32x4*)dst = w;
    } else {                                 // x : [128][4096] -> xTf A-frags (transpose)
        const int t = i - 73728;             // [0, 65536)
        const int n = t & 4095, g = (t >> 12) & 3, cblk = t >> 14;
        const int c0 = cblk * 32 + g * 4;
        const float* xs = x + (size_t)c0 * 4096 + n;
        u32x4 w;
        #pragma unroll
        for (int j = 0; j < 4; ++j)
            w[j] = ((unsigned int)f2bf_bits(xs[(size_t)(16 + j) * 4096]) << 16)
                 | f2bf_bits(xs[(size_t)j * 4096]);
        bf16* dst = xTf + ((((n >> 4) << 2) + cblk) * 512 + ((g << 4) + (n & 15)) * 8);
        *(u32x4*)dst = w;
    }
}

// ---------------- K1: QKV — barrier-free fragment-streaming GEMM (R14) ----------------
__global__ void __launch_bounds__(256) k_qkv(
    const bf16* __restrict__ xTf, const bf16* __restrict__ Wqkvf,
    const float* __restrict__ bq, const float* __restrict__ bk, const float* __restrict__ bv,
    bf16* __restrict__ qf, bf16* __restrict__ kf, bf16* __restrict__ vf)
{
    const int tid = threadIdx.x, wave = tid >> 6, lane = tid & 63;
    const int col = lane & 15, quad = lane >> 4;
    const int gw = blockIdx.x * 4 + wave;     // [0, 6144)
    const int rt = gw / 24, ct = gw % 24;
    f32x4 acc = {};
    #pragma unroll
    for (int c = 0; c < 4; ++c) {
        short8 a = *(const short8*)(xTf + ((size_t)(rt * 4 + c) << 9) + lane * 8);
        short8 b = *(const short8*)(Wqkvf + ((size_t)(ct * 4 + c) << 9) + lane * 8);
        acc = mfma16(a, b, acc);
    }
    #pragma unroll
    for (int r = 0; r < 4; ++r) {
        const int m = rt * 16 + quad * 4 + r;
        const int n = ct * 16 + col;
        const float v = acc[r];
        if (n < 128) {
            const int h = n >> 4, ch = n & 15;
            qf[((h << 8) + (m >> 4)) * 256 + (((ch >> 3) << 4) + (m & 15)) * 8 + (ch & 7)] =
                __float2bfloat16((v + bq[n]) * SCALE_Q);
        } else if (n < 256) {
            const int c2 = n - 128, h = c2 >> 4, ch = c2 & 15;
            kf[((h << 8) + (m >> 4)) * 256 + (((ch >> 3) << 4) + (m & 15)) * 8 + (ch & 7)] =
                __float2bfloat16(v + bk[c2]);
        } else {
            const int c2 = n - 256, h = c2 >> 4, ch = c2 & 15;
            const int ko = m & 31;
            const int pos = ((ko & 15) << 1) + (ko >> 4);
            vf[((h << 7) + (m >> 5)) * 512 + (((pos >> 3) << 4) + ch) * 8 + (pos & 7)] =
                __float2bfloat16(v + bv[c2]);
        }
    }
}

// ---------------- K2: MFMA flash attention — q-tile grouping for KV L2 reuse (R14) ------
__global__ void __launch_bounds__(256)
attn_kernel(const bf16* __restrict__ qf, const bf16* __restrict__ kf,
            const bf16* __restrict__ vf, bf16* __restrict__ af)
{
    __shared__ __align__(16) union {
        unsigned int P[4][4][2][320];   // [wave][qt][buf] transpose bufs, 40 KB
        float comb[4][4][64][8];        // [qt][wave][lane][O0..3,L0..3], 32 KB
    } sh;
    const int tid = threadIdx.x, wave = tid >> 6, lane = tid & 63;
    const int col = lane & 15, quad = lane >> 4;
    const int gw = blockIdx.x;                   // [0, 512)
    const int h  = gw >> 6;
    const int tile0 = (gw & 63) << 2;
    const f32x4 zero = {};

    short8 aq[4] = {{}, {}, {}, {}};
    if (quad < 2) {
        #pragma unroll
        for (int qt = 0; qt < 4; ++qt)
            aq[qt] = *(const short8*)(qf + ((size_t)((h << 8) + tile0 + qt) << 8) + lane * 8);
    }

    const short8 onesb = { (short)0x3F80, (short)0x3F80, (short)0x3F80, (short)0x3F80,
                           (short)0x3F80, (short)0x3F80, (short)0x3F80, (short)0x3F80 };

    f32x4 accO[4] = {{}, {}, {}, {}};
    f32x4 accL[4] = {{}, {}, {}, {}};

    const int kbeg = wave << 10;

    for (int i = 0; i < 32; i += 2) {
        const int mA = kbeg + (i << 5);
        const int mB = mA + 32;

        short8 bkA0 = {}, bkA1 = {}, bkB0 = {}, bkB1 = {};
        if (quad < 2) {
            const bf16* ka = kf + ((size_t)((h << 8) + (mA >> 4)) << 8) + lane * 8;
            bkA0 = *(const short8*)(ka);
            bkA1 = *(const short8*)(ka + 256);
            bkB0 = *(const short8*)(ka + 512);
            bkB1 = *(const short8*)(ka + 768);
        }
        const short8 vA = *(const short8*)(vf + ((size_t)((h << 7) + (mA >> 5)) << 9) + lane * 8);
        const short8 vB = *(const short8*)(vf + ((size_t)((h << 7) + (mB >> 5)) << 9) + lane * 8);

        #pragma unroll
        for (int qt = 0; qt < 4; ++qt) {
            f32x4 s0 = mfma16(aq[qt], bkA0, zero);
            f32x4 s1 = mfma16(aq[qt], bkA1, zero);
            f32x4 s2 = mfma16(aq[qt], bkB0, zero);
            f32x4 s3 = mfma16(aq[qt], bkB1, zero);
            unsigned int* P0 = &sh.P[wave][qt][0][0];
            unsigned int* P1 = &sh.P[wave][qt][1][0];
            #pragma unroll
            for (int r = 0; r < 4; ++r) {
                P0[(quad * 4 + r) * 20 + col] = pack_trunc(fast_exp2(s0[r]), fast_exp2(s1[r]));
                P1[(quad * 4 + r) * 20 + col] = pack_trunc(fast_exp2(s2[r]), fast_exp2(s3[r]));
            }
        }
        #pragma unroll
        for (int qt = 0; qt < 4; ++qt) {
            const short* Ps0 = (const short*)&sh.P[wave][qt][0][0];
            const short* Ps1 = (const short*)&sh.P[wave][qt][1][0];
            short8 ap0 = *(const short8*)(Ps0 + col * 40 + quad * 8);
            accO[qt] = mfma16(ap0, vA, accO[qt]);
            accL[qt] = mfma16(ap0, onesb, accL[qt]);
            short8 ap1 = *(const short8*)(Ps1 + col * 40 + quad * 8);
            accO[qt] = mfma16(ap1, vB, accO[qt]);
            accL[qt] = mfma16(ap1, onesb, accL[qt]);
        }
    }

    __syncthreads();
    #pragma unroll
    for (int qt = 0; qt < 4; ++qt)
        #pragma unroll
        for (int r = 0; r < 4; ++r) {
            sh.comb[qt][wave][lane][r]     = accO[qt][r];
            sh.comb[qt][wave][lane][4 + r] = accL[qt][r];
        }
    __syncthreads();

    {   // wave w finalizes q-tile w
        const int qt = wave, tile = tile0 + qt;
        #pragma unroll
        for (int r = 0; r < 4; ++r) {
            float O = sh.comb[qt][0][lane][r] + sh.comb[qt][1][lane][r]
                    + sh.comb[qt][2][lane][r] + sh.comb[qt][3][lane][r];
            float l = sh.comb[qt][0][lane][4+r] + sh.comb[qt][1][lane][4+r]
                    + sh.comb[qt][2][lane][4+r] + sh.comb[qt][3][lane][4+r];
            const int row16 = quad * 4 + r;
            const int pk = (col << 1) + (h & 1);
            af[((tile << 2) + (h >> 1)) * 512 + (((pk >> 3) << 4) + row16) * 8 + (pk & 7)] =
                __float2bfloat16(O / l);
        }
    }
}

// ---------------- K3: MEGA — 8 waves (R13 shape); R20: COALESCED out stores -------------
// R17 counters finally decoded: WRITE_SIZE 51 MB/rep vs 2 MB logical (25x) — the old
// epilogue scattered 4B stores at 16KB stride (ch varies per lane), so every wave store
// touched 64 lines. Write-allocate fetches for those lines also poisoned FETCH (~32 MB)
// and evicted the 1 MB weight set from L2 (the "impossible" 60% miss rate). This is why
// all compute/TLP/stream fixes (R12/R13/R16/R18/R19) were neutral.
// Fix: wave0 writes post-LN2 values to LDS ot[ch][nl] (stride 17 = conflict-free), then
// ALL 512 threads store coalesced: thread j -> (ch=j>>2, seg=j&3), one dwordx4; 4 threads
// fill each 64B line completely. Identical arithmetic -> bit-identical output.
__global__ void __launch_bounds__(512, 2)
k_mega(const bf16* __restrict__ af, const bf16* __restrict__ xTf,
       const bf16* __restrict__ Wof, const bf16* __restrict__ W1f, const bf16* __restrict__ W2f,
       const float* __restrict__ bo, const float* __restrict__ b1, const float* __restrict__ b2,
       const float* __restrict__ g1, const float* __restrict__ be1,
       const float* __restrict__ g2, const float* __restrict__ be2,
       float* __restrict__ out)
{
    __shared__ __align__(16) unsigned int Pb[8][2][320];   // per-wave transpose dbuf (20 KB)
    __shared__ float comb[224][64];                         // ffn2 partials, waves 1-7 (56 KB)
    __shared__ float ot[128 * 17];                          // out staging, stride 17 (8.5 KB)
    const int tid = threadIdx.x, wave = tid >> 6, lane = tid & 63;
    const int col = lane & 15, quad = lane >> 4;
    const int rt = blockIdx.x, n0 = rt << 4;
    const f32x4 zero = {};

    // ---- oproj: D = attn_frag . Wo^T  (each wave redundantly; 32 MFMA, cheap) ----
    short8 ao[4], xt[4];
    #pragma unroll
    for (int c = 0; c < 4; ++c) {
        ao[c] = *(const short8*)(af  + ((size_t)(rt * 4 + c) << 9) + lane * 8);
        xt[c] = *(const short8*)(xTf + ((size_t)(rt * 4 + c) << 9) + lane * 8);
    }
    f32x4 d[8];
    #pragma unroll
    for (int t = 0; t < 8; ++t) d[t] = zero;
    #pragma unroll
    for (int t = 0; t < 8; ++t)
        #pragma unroll
        for (int c = 0; c < 4; ++c) {
            short8 b = *(const short8*)(Wof + ((size_t)(t * 4 + c) << 9) + lane * 8);
            d[t] = mfma16(ao[c], b, d[t]);
        }
    #pragma unroll
    for (int t = 0; t < 8; ++t) {
        const float bt = bo[t * 16 + col];
        #pragma unroll
        for (int r = 0; r < 4; ++r) d[t][r] += bt;
    }

    // ---- D->A transpose via wave-private LDS; add residual x ----
    float x1f[4][8];
    #pragma unroll
    for (int c = 0; c < 4; ++c) {
        unsigned int* Pw = &Pb[wave][c & 1][0];
        const short* Ps = (const short*)Pw;
        #pragma unroll
        for (int r = 0; r < 4; ++r)
            Pw[(quad * 4 + r) * 20 + col] = pack_trunc(d[2 * c][r], d[2 * c + 1][r]);
        short8 ar = *(const short8*)(Ps + col * 40 + quad * 8);
        #pragma unroll
        for (int j = 0; j < 8; ++j)
            x1f[c][j] = bfs2f(ar[j]) + bfs2f(xt[c][j]);
    }

    // ---- LN1 (redundant in every wave; shfl-only) ----
    float s = 0.f, ss = 0.f;
    #pragma unroll
    for (int c = 0; c < 4; ++c)
        #pragma unroll
        for (int j = 0; j < 8; ++j) { s += x1f[c][j]; ss += x1f[c][j] * x1f[c][j]; }
    s  += __shfl_xor(s, 16);  s  += __shfl_xor(s, 32);
    ss += __shfl_xor(ss, 16); ss += __shfl_xor(ss, 32);
    const float m1 = s * (1.f / 128.f);
    const float rstd1 = rsqrtf(ss * (1.f / 128.f) - m1 * m1 + 1e-5f);
    short8 aq1[4];
    #pragma unroll
    for (int c = 0; c < 4; ++c)
        #pragma unroll
        for (int j = 0; j < 8; ++j) {
            const int pos = quad * 8 + j;
            const int ko = ((pos & 1) << 4) + (pos >> 1);
            const int ch = c * 32 + ko;
            aq1[c][j] = f2bf_trunc((x1f[c][j] - m1) * rstd1 * g1[ch] + be1[ch]);
        }

    // ---- FFN: this wave owns FF range [wave*256, +256) = 8 chunks of 32 ----
    f32x4 ACC[8];
    #pragma unroll
    for (int t = 0; t < 8; ++t) ACC[t] = zero;
    for (int i = 0; i < 8; ++i) {
        const int ffc = (wave << 3) + i;                  // global 32-FF chunk [0,64)
        f32x4 p0 = zero, p1 = zero;
        #pragma unroll
        for (int c = 0; c < 4; ++c) {
            short8 b = *(const short8*)(W1f + ((size_t)(ffc * 8 + c) << 9) + lane * 8);
            p0 = mfma16(aq1[c], b, p0);
        }
        #pragma unroll
        for (int c = 0; c < 4; ++c) {
            short8 b = *(const short8*)(W1f + ((size_t)(ffc * 8 + 4 + c) << 9) + lane * 8);
            p1 = mfma16(aq1[c], b, p1);
        }
        const float bb0 = b1[ffc * 32 + col], bb1 = b1[ffc * 32 + 16 + col];
        unsigned int* Pw = &Pb[wave][i & 1][0];
        #pragma unroll
        for (int r = 0; r < 4; ++r)
            Pw[(quad * 4 + r) * 20 + col] =
                pack_trunc(fmaxf(p0[r] + bb0, 0.f), fmaxf(p1[r] + bb1, 0.f));
        short8 ah = *(const short8*)((const short*)Pw + col * 40 + quad * 8);
        #pragma unroll
        for (int t = 0; t < 8; ++t) {
            short8 bw = *(const short8*)(W2f + ((size_t)(t * 64 + ffc) << 9) + lane * 8);
            ACC[t] = mfma16(ah, bw, ACC[t]);
        }
    }

    // ---- tree-combine ffn2 partials; wave0: residual + LN2 -> LDS ----
    if (wave) {
        #pragma unroll
        for (int t = 0; t < 8; ++t)
            #pragma unroll
            for (int r = 0; r < 4; ++r)
                comb[(wave - 1) * 32 + t * 4 + r][lane] = ACC[t][r];
    }
    __syncthreads();
    if (wave == 0) {
        #pragma unroll
        for (int t = 0; t < 8; ++t)
            #pragma unroll
            for (int r = 0; r < 4; ++r) {
                float acc = ACC[t][r];
                #pragma unroll
                for (int w = 0; w < 7; ++w)
                    acc += comb[w * 32 + t * 4 + r][lane];
                ACC[t][r] = acc;
            }
        short* xb = (short*)&Pb[0][0][0];   // [row16][chunk][32 pk] = 4096 shorts
        #pragma unroll
        for (int c = 0; c < 4; ++c)
            *(short8*)(xb + (col * 4 + c) * 32 + quad * 8) = aq1[c];
        float t2[8][4];
        #pragma unroll
        for (int t = 0; t < 8; ++t) {
            const int ch = t * 16 + col;
            const int pk = (col << 1) + (t & 1);
            const int c = t >> 1;
            const float bb = b2[ch];
            #pragma unroll
            for (int r = 0; r < 4; ++r)
                t2[t][r] = ACC[t][r] + bb + bfs2f(xb[((quad * 4 + r) * 4 + c) * 32 + pk]);
        }
        #pragma unroll
        for (int r = 0; r < 4; ++r) {
            float S = 0.f, SS = 0.f;
            #pragma unroll
            for (int t = 0; t < 8; ++t) { S += t2[t][r]; SS += t2[t][r] * t2[t][r]; }
            S  += __shfl_xor(S, 1);  S  += __shfl_xor(S, 2);
            S  += __shfl_xor(S, 4);  S  += __shfl_xor(S, 8);
            SS += __shfl_xor(SS, 1); SS += __shfl_xor(SS, 2);
            SS += __shfl_xor(SS, 4); SS += __shfl_xor(SS, 8);
            const float m2 = S * (1.f / 128.f);
            const float rstd2 = rsqrtf(SS * (1.f / 128.f) - m2 * m2 + 1e-5f);
            #pragma unroll
            for (int t = 0; t < 8; ++t) {
                const int ch = t * 16 + col;
                ot[ch * 17 + quad * 4 + r] = (t2[t][r] - m2) * rstd2 * g2[ch] + be2[ch];
            }
        }
    }
    __syncthreads();
    {   // coalesced store: thread j -> ch = j>>2, 4 floats at n0 + (j&3)*4
        const int ch = tid >> 2, seg = tid & 3;
        f32x4 v;
        #pragma unroll
        for (int k = 0; k < 4; ++k)
            v[k] = ot[ch * 17 + seg * 4 + k];
        *(f32x4*)(out + (size_t)ch * N_ + n0 + seg * 4) = v;
    }
}

extern "C" void kernel_launch(void* const* d_in, const int* in_sizes, int n_in,
                              void* d_out, int out_size, void* d_ws, size_t ws_size,
                              hipStream_t stream) {
    const float* x   = (const float*)d_in[0];
    const float* Wq  = (const float*)d_in[1];
    const float* bq  = (const float*)d_in[2];
    const float* Wk  = (const float*)d_in[3];
    const float* bk  = (const float*)d_in[4];
    const float* Wv  = (const float*)d_in[5];
    const float* bv  = (const float*)d_in[6];
    const float* Wo  = (const float*)d_in[7];
    const float* bo  = (const float*)d_in[8];
    const float* W1  = (const float*)d_in[9];
    const float* b1  = (const float*)d_in[10];
    const float* W2  = (const float*)d_in[11];
    const float* b2  = (const float*)d_in[12];
    const float* g1  = (const float*)d_in[13];
    const float* be1 = (const float*)d_in[14];
    const float* g2  = (const float*)d_in[15];
    const float* be2 = (const float*)d_in[16];
    float* out = (float*)d_out;

    char* ws = (char*)d_ws;
    bf16* xTf   = (bf16*)(ws + 0);          // 1 MB
    bf16* qf    = (bf16*)(ws + 1048576);    // 1 MB
    bf16* kf    = (bf16*)(ws + 2097152);    // 1 MB
    bf16* vf    = (bf16*)(ws + 3145728);    // 1 MB
    bf16* af    = (bf16*)(ws + 4194304);    // 1 MB
    bf16* Wqkvf = (bf16*)(ws + 5242880);    // 96 KB
    bf16* Wof   = (bf16*)(ws + 5341184);    // 32 KB
    bf16* W1f   = (bf16*)(ws + 5373952);    // 512 KB
    bf16* W2f   = (bf16*)(ws + 5898240);    // 512 KB

    k_prep<<<544, 256, 0, stream>>>(Wq, Wk, Wv, Wo, W1, W2, x, Wqkvf, Wof, W1f, W2f, xTf);
    k_qkv<<<1536, 256, 0, stream>>>(xTf, Wqkvf, bq, bk, bv, qf, kf, vf);
    attn_kernel<<<512, 256, 0, stream>>>(qf, kf, vf, af);
    k_mega<<<256, 512, 0, stream>>>(af, xTf, Wof, W1f, W2f, bo, b1, b2,
                                    g1, be1, g2, be2, out);
}